// Round 2
// baseline (2299.123 us; speedup 1.0000x reference)
//
#include <hip/hip_runtime.h>

#define TNODES 32768
#define NEDGE  1048576
#define HD     128
#define NG     512     // 4*H gates
#define NB     64
#define SEQ    512
#define FCN    262144  // N_NODES^2

// ---------------------------------------------------------------- GCN: degree
__global__ __launch_bounds__(256) void k_deg(const int* __restrict__ ei,
                                             const float* __restrict__ ew,
                                             float* __restrict__ deg,
                                             int* __restrict__ cnt) {
    int e = blockIdx.x * 256 + threadIdx.x;
    int d = ei[NEDGE + e];          // dst row
    atomicAdd(&deg[d], ew[e]);
    atomicAdd(&cnt[d], 1);
}

__global__ __launch_bounds__(256) void k_dinv(float* __restrict__ deg) {
    int n = blockIdx.x * 256 + threadIdx.x;
    deg[n] = rsqrtf(deg[n] + 1.0f);   // self-loop w=1; deg>=1 always
}

// exclusive prefix scan of cnt[32768] -> offs[32769], single block
__global__ __launch_bounds__(1024) void k_scan(const int* __restrict__ cnt,
                                               int* __restrict__ offs) {
    __shared__ int sums[1024];
    int t = threadIdx.x;
    int base = t * 32;
    int local[32];
    int s = 0;
    #pragma unroll
    for (int j = 0; j < 32; ++j) { local[j] = s; s += cnt[base + j]; }
    sums[t] = s;
    __syncthreads();
    for (int off = 1; off < 1024; off <<= 1) {
        int v = sums[t];
        int u = (t >= off) ? sums[t - off] : 0;
        __syncthreads();
        sums[t] = v + u;
        __syncthreads();
    }
    int baseSum = (t == 0) ? 0 : sums[t - 1];
    #pragma unroll
    for (int j = 0; j < 32; ++j) offs[base + j] = baseSum + local[j];
    if (t == 1023) offs[TNODES] = sums[1023];
}

__global__ __launch_bounds__(256) void k_fill(const int* __restrict__ ei,
                                              const float* __restrict__ ew,
                                              const float* __restrict__ dinv,
                                              const int* __restrict__ offs,
                                              int* __restrict__ cursor,
                                              int* __restrict__ csrc,
                                              float* __restrict__ ca) {
    int e = blockIdx.x * 256 + threadIdx.x;
    int s = ei[e];
    int d = ei[NEDGE + e];
    int p = offs[d] + atomicAdd(&cursor[d], 1);
    csrc[p] = s;
    ca[p] = ew[e] * dinv[s];
}

// ------------------------------------------------- tiny transpose W_gcn -> Wt
__global__ __launch_bounds__(256) void k_transpose(const float* __restrict__ W,
                                                   float* __restrict__ Wt) {
    int t = blockIdx.x * 256 + threadIdx.x;   // 16384
    int c = t >> 7, k = t & 127;
    Wt[t] = W[k * HD + c];
}

// -------------------------------------------- generic C[R,G] = A[R,128]@Bt^T
// Bt is [G,128]; bias = bias1[g]+bias2[g] (either may be null). 64x64 tiles.
#define GS 140
__global__ __launch_bounds__(256) void k_gemm_bt(const float* __restrict__ A,
                                                 const float* __restrict__ Bt,
                                                 const float* __restrict__ b1,
                                                 const float* __restrict__ b2,
                                                 float* __restrict__ C, int G) {
    __shared__ __align__(16) float As[64 * GS];
    __shared__ __align__(16) float Bs[64 * GS];
    int r0 = blockIdx.x * 64;
    int g0 = blockIdx.y * 64;
    int tid = threadIdx.x;
    #pragma unroll
    for (int it = 0; it < 8; ++it) {
        int idx = tid + 256 * it;        // 0..2047
        int r = idx >> 5, c4 = idx & 31;
        float4 va = ((const float4*)(A + (size_t)(r0 + r) * HD))[c4];
        *((float4*)&As[r * GS + c4 * 4]) = va;
        float4 vb = ((const float4*)(Bt + (size_t)(g0 + r) * HD))[c4];
        *((float4*)&Bs[r * GS + c4 * 4]) = vb;
    }
    __syncthreads();
    int i = tid >> 4;    // 0..15 -> rows i + 16*mi
    int j = tid & 15;    // 0..15 -> cols j + 16*ni
    float acc[4][4];
    #pragma unroll
    for (int a = 0; a < 4; ++a)
        #pragma unroll
        for (int b = 0; b < 4; ++b) acc[a][b] = 0.f;
    #pragma unroll 8
    for (int k4 = 0; k4 < 32; ++k4) {
        float4 av[4], bv[4];
        #pragma unroll
        for (int mi = 0; mi < 4; ++mi)
            av[mi] = *((const float4*)&As[(i + 16 * mi) * GS + k4 * 4]);
        #pragma unroll
        for (int ni = 0; ni < 4; ++ni)
            bv[ni] = *((const float4*)&Bs[(j + 16 * ni) * GS + k4 * 4]);
        #pragma unroll
        for (int mi = 0; mi < 4; ++mi)
            #pragma unroll
            for (int ni = 0; ni < 4; ++ni)
                acc[mi][ni] += (av[mi].x * bv[ni].x + av[mi].y * bv[ni].y) +
                               (av[mi].z * bv[ni].z + av[mi].w * bv[ni].w);
    }
    #pragma unroll
    for (int mi = 0; mi < 4; ++mi)
        #pragma unroll
        for (int ni = 0; ni < 4; ++ni) {
            int g = g0 + j + 16 * ni;
            float bias = (b1 ? b1[g] : 0.f) + (b2 ? b2[g] : 0.f);
            C[(size_t)(r0 + i + 16 * mi) * G + g] = acc[mi][ni] + bias;
        }
}

// ------------------------------------------------------------ GCN aggregation
__global__ __launch_bounds__(128) void k_agg(const int* __restrict__ offs,
                                             const int* __restrict__ csrc,
                                             const float* __restrict__ ca,
                                             const float* __restrict__ xw,
                                             const float* __restrict__ dinv,
                                             const float* __restrict__ bg,
                                             float* __restrict__ hg) {
    int d = blockIdx.x;
    int t = threadIdx.x;
    int beg = offs[d], end = offs[d + 1];
    float acc = 0.f;
    int e = beg;
    for (; e + 3 < end; e += 4) {
        int s0 = csrc[e], s1 = csrc[e + 1], s2 = csrc[e + 2], s3 = csrc[e + 3];
        float a0 = ca[e], a1 = ca[e + 1], a2 = ca[e + 2], a3 = ca[e + 3];
        acc += a0 * xw[(size_t)s0 * HD + t];
        acc += a1 * xw[(size_t)s1 * HD + t];
        acc += a2 * xw[(size_t)s2 * HD + t];
        acc += a3 * xw[(size_t)s3 * HD + t];
    }
    for (; e < end; ++e) acc += ca[e] * xw[(size_t)csrc[e] * HD + t];
    float di = dinv[d];
    hg[(size_t)d * HD + t] = di * acc + di * di * xw[(size_t)d * HD + t] + bg[t];
}

// ----------------------------------------------------------------- LSTM scan
__device__ __forceinline__ float sigm(float x) { return 1.f / (1.f + __expf(-x)); }
__device__ __forceinline__ float tanh_s(float x) {
    float e = __expf(-2.f * fabsf(x));
    float t = (1.f - e) / (1.f + e);
    return copysignf(t, x);
}

// component select that folds to a direct member access under full unroll
#define COMP(v, j) ((j) == 0 ? (v).x : ((j) == 1 ? (v).y : ((j) == 2 ? (v).z : (v).w)))

// 256 threads; thread t owns gate rows t and t+256 of whh.
// h broadcast via v_readlane (VALU pipe) instead of LDS reads.
__global__ __launch_bounds__(256, 1) void k_lstm(const float* __restrict__ P,
                                                 const float* __restrict__ whh,
                                                 float* __restrict__ Hout,
                                                 float* __restrict__ lastOut) {
    __shared__ __align__(16) float h_sh[HD];
    __shared__ float g_sh[NG];
    int b = blockIdx.x, t = threadIdx.x;
    int lane = t & 63;

    float4 wA[32], wB[32];
    const float4* rowA = (const float4*)(whh + (size_t)t * HD);
    const float4* rowB = (const float4*)(whh + (size_t)(t + 256) * HD);
    #pragma unroll
    for (int k = 0; k < 32; ++k) { wA[k] = rowA[k]; wB[k] = rowB[k]; }
    // pin weights into VGPRs — prevents per-step re-load (VGPR_Count=80 pathology)
    #pragma unroll
    for (int k = 0; k < 32; ++k) {
        asm volatile("" : "+v"(wA[k].x), "+v"(wA[k].y), "+v"(wA[k].z), "+v"(wA[k].w));
        asm volatile("" : "+v"(wB[k].x), "+v"(wB[k].y), "+v"(wB[k].z), "+v"(wB[k].w));
    }

    float c = 0.f;
    if (t < HD) h_sh[t] = 0.f;
    __syncthreads();

    const float* Pb = P + (size_t)b * SEQ * NG;
    float p0 = Pb[t], p1 = Pb[256 + t];

    for (int s = 0; s < SEQ; ++s) {
        // prefetch next step's P (hidden behind the dot-product)
        const float* Pn = Pb + (size_t)((s + 1 < SEQ) ? (s + 1) : s) * NG;
        float q0 = Pn[t], q1 = Pn[256 + t];

        // wave-local copy of h: 2 conflict-free LDS reads per thread
        float hv0 = h_sh[lane];
        float hv1 = h_sh[64 + lane];

        float accA[4] = {0.f, 0.f, 0.f, 0.f};
        float accB[4] = {0.f, 0.f, 0.f, 0.f};
        #pragma unroll
        for (int k = 0; k < 64; ++k) {
            float h = __int_as_float(__builtin_amdgcn_readlane(__float_as_int(hv0), k));
            accA[k & 3] = fmaf(COMP(wA[k >> 2], k & 3), h, accA[k & 3]);
            accB[k & 3] = fmaf(COMP(wB[k >> 2], k & 3), h, accB[k & 3]);
        }
        #pragma unroll
        for (int k = 0; k < 64; ++k) {
            float h = __int_as_float(__builtin_amdgcn_readlane(__float_as_int(hv1), k));
            accA[k & 3] = fmaf(COMP(wA[16 + (k >> 2)], k & 3), h, accA[k & 3]);
            accB[k & 3] = fmaf(COMP(wB[16 + (k >> 2)], k & 3), h, accB[k & 3]);
        }
        float rawA = ((accA[0] + accA[1]) + (accA[2] + accA[3])) + p0;
        float rawB = ((accB[0] + accB[1]) + (accB[2] + accB[3])) + p1;

        // row A = gates [0,256) -> i (t<128) or f (t>=128): sigmoid
        // row B = gates [256,512) -> g (t<128): tanh, o (t>=128): sigmoid
        float gA = sigm(rawA);
        float gB = (t < 128) ? tanh_s(rawB) : sigm(rawB);
        g_sh[t] = gA;
        g_sh[256 + t] = gB;
        __syncthreads();

        if (t < HD) {
            float i_ = g_sh[t], f_ = g_sh[128 + t], gg = g_sh[256 + t], o_ = g_sh[384 + t];
            c = fmaf(f_, c, i_ * gg);
            float h = o_ * tanh_s(c);
            h_sh[t] = h;
            if (Hout) Hout[((size_t)b * SEQ + s) * HD + t] = h;
            if (lastOut && s == SEQ - 1) lastOut[b * HD + t] = h;
        }
        __syncthreads();
        p0 = q0;
        p1 = q1;
    }
}

// ----------------------------------------------------------------------- FC
__global__ __launch_bounds__(256) void k_fc(const float* __restrict__ last,
                                            const float* __restrict__ fcw,
                                            const float* __restrict__ fcb,
                                            float* __restrict__ out) {
    __shared__ __align__(16) float l_sh[NB * HD];
    int tid = threadIdx.x;
    #pragma unroll
    for (int it = 0; it < 32; ++it) l_sh[tid + 256 * it] = last[tid + 256 * it];
    __syncthreads();
    int i = blockIdx.x * 256 + tid;
    const float4* wrow = (const float4*)(fcw + (size_t)i * HD);
    float acc[NB];
    #pragma unroll
    for (int b = 0; b < NB; ++b) acc[b] = 0.f;
    for (int k4 = 0; k4 < 32; ++k4) {
        float4 w4 = wrow[k4];
        #pragma unroll
        for (int b = 0; b < NB; ++b) {
            float4 l4 = ((const float4*)(l_sh + b * HD))[k4];
            acc[b] += (w4.x * l4.x + w4.y * l4.y) + (w4.z * l4.z + w4.w * l4.w);
        }
    }
    float bias = fcb[i];
    #pragma unroll
    for (int b = 0; b < NB; ++b) out[(size_t)b * FCN + i] = acc[b] + bias;
}

// -------------------------------------------------------------------- launch
extern "C" void kernel_launch(void* const* d_in, const int* in_sizes, int n_in,
                              void* d_out, int out_size, void* d_ws, size_t ws_size,
                              hipStream_t stream) {
    const float* x   = (const float*)d_in[0];
    const int*   ei  = (const int*)d_in[1];
    const float* ew  = (const float*)d_in[2];
    const float* Wg  = (const float*)d_in[4];
    const float* bg  = (const float*)d_in[5];
    const float* wih = (const float*)d_in[6];   // [2,512,128]
    const float* whh = (const float*)d_in[7];   // [2,512,128]
    const float* bih = (const float*)d_in[8];   // [2,512]
    const float* bhh = (const float*)d_in[9];
    const float* fcw = (const float*)d_in[10];  // [262144,128]
    const float* fcb = (const float*)d_in[11];
    float* out = (float*)d_out;

    float* ws = (float*)d_ws;
    float* deg    = ws;                         // 32768 (-> dinv in place)
    int*   cnt    = (int*)(ws + 32768);         // 32768
    int*   cursor = (int*)(ws + 65536);         // 32768
    int*   offs   = (int*)(ws + 98304);         // 32769
    int*   csrc   = (int*)(ws + 131136);        // 1048576
    float* ca     = ws + 1179712;               // 1048576
    float* Wt     = ws + 2228288;               // 16384
    float* xw     = ws + 2244672;               // 4194304
    float* hg     = ws + 6438976;               // 4194304
    float* H0     = ws + 10633280;              // 4194304
    float* lastb  = ws + 14827584;              // 8192
    float* P      = ws + 14835776;              // 16777216

    // zero deg, cnt, cursor in one shot
    hipMemsetAsync(d_ws, 0, 3 * 32768 * sizeof(float), stream);

    k_deg<<<NEDGE / 256, 256, 0, stream>>>(ei, ew, deg, cnt);
    k_dinv<<<TNODES / 256, 256, 0, stream>>>(deg);
    k_scan<<<1, 1024, 0, stream>>>(cnt, offs);
    k_fill<<<NEDGE / 256, 256, 0, stream>>>(ei, ew, deg, offs, cursor, csrc, ca);
    k_transpose<<<64, 256, 0, stream>>>(Wg, Wt);
    k_gemm_bt<<<dim3(TNODES / 64, HD / 64), 256, 0, stream>>>(x, Wt, nullptr, nullptr, xw, HD);
    k_agg<<<TNODES, 128, 0, stream>>>(offs, csrc, ca, xw, deg, bg, hg);

    // layer 0
    k_gemm_bt<<<dim3(TNODES / 64, NG / 64), 256, 0, stream>>>(hg, wih, bih, bhh, P, NG);
    k_lstm<<<NB, 256, 0, stream>>>(P, whh, H0, nullptr);
    // layer 1
    k_gemm_bt<<<dim3(TNODES / 64, NG / 64), 256, 0, stream>>>(H0, wih + 65536, bih + 512, bhh + 512, P, NG);
    k_lstm<<<NB, 256, 0, stream>>>(P, whh + 65536, nullptr, lastb);

    k_fc<<<FCN / 256, 256, 0, stream>>>(lastb, fcw, fcb, out);
}

// Round 3
// 2146.301 us; speedup vs baseline: 1.0712x; 1.0712x over previous
//
#include <hip/hip_runtime.h>

#define TNODES 32768
#define NEDGE  1048576
#define HD     128
#define NG     512     // 4*H gates
#define NB     64
#define SEQ    512
#define FCN    262144  // N_NODES^2

// ---------------------------------------------------------------- GCN: degree
__global__ __launch_bounds__(256) void k_deg(const int* __restrict__ ei,
                                             const float* __restrict__ ew,
                                             float* __restrict__ deg,
                                             int* __restrict__ cnt) {
    int e = blockIdx.x * 256 + threadIdx.x;
    int d = ei[NEDGE + e];          // dst row
    atomicAdd(&deg[d], ew[e]);
    atomicAdd(&cnt[d], 1);
}

__global__ __launch_bounds__(256) void k_dinv(float* __restrict__ deg) {
    int n = blockIdx.x * 256 + threadIdx.x;
    deg[n] = rsqrtf(deg[n] + 1.0f);   // self-loop w=1; deg>=1 always
}

// exclusive prefix scan of cnt[32768] -> offs[32769], single block
__global__ __launch_bounds__(1024) void k_scan(const int* __restrict__ cnt,
                                               int* __restrict__ offs) {
    __shared__ int sums[1024];
    int t = threadIdx.x;
    int base = t * 32;
    int local[32];
    int s = 0;
    #pragma unroll
    for (int j = 0; j < 32; ++j) { local[j] = s; s += cnt[base + j]; }
    sums[t] = s;
    __syncthreads();
    for (int off = 1; off < 1024; off <<= 1) {
        int v = sums[t];
        int u = (t >= off) ? sums[t - off] : 0;
        __syncthreads();
        sums[t] = v + u;
        __syncthreads();
    }
    int baseSum = (t == 0) ? 0 : sums[t - 1];
    #pragma unroll
    for (int j = 0; j < 32; ++j) offs[base + j] = baseSum + local[j];
    if (t == 1023) offs[TNODES] = sums[1023];
}

__global__ __launch_bounds__(256) void k_fill(const int* __restrict__ ei,
                                              const float* __restrict__ ew,
                                              const float* __restrict__ dinv,
                                              const int* __restrict__ offs,
                                              int* __restrict__ cursor,
                                              int* __restrict__ csrc,
                                              float* __restrict__ ca) {
    int e = blockIdx.x * 256 + threadIdx.x;
    int s = ei[e];
    int d = ei[NEDGE + e];
    int p = offs[d] + atomicAdd(&cursor[d], 1);
    csrc[p] = s;
    ca[p] = ew[e] * dinv[s];
}

// ------------------------------------------------- tiny transpose W_gcn -> Wt
__global__ __launch_bounds__(256) void k_transpose(const float* __restrict__ W,
                                                   float* __restrict__ Wt) {
    int t = blockIdx.x * 256 + threadIdx.x;   // 16384
    int c = t >> 7, k = t & 127;
    Wt[t] = W[k * HD + c];
}

// -------------------------------------------- generic C[R,G] = A[R,128]@Bt^T
// Bt is [G,128]; bias = bias1[g]+bias2[g] (either may be null). 64x64 tiles.
#define GS 140
__global__ __launch_bounds__(256) void k_gemm_bt(const float* __restrict__ A,
                                                 const float* __restrict__ Bt,
                                                 const float* __restrict__ b1,
                                                 const float* __restrict__ b2,
                                                 float* __restrict__ C, int G) {
    __shared__ __align__(16) float As[64 * GS];
    __shared__ __align__(16) float Bs[64 * GS];
    int r0 = blockIdx.x * 64;
    int g0 = blockIdx.y * 64;
    int tid = threadIdx.x;
    #pragma unroll
    for (int it = 0; it < 8; ++it) {
        int idx = tid + 256 * it;        // 0..2047
        int r = idx >> 5, c4 = idx & 31;
        float4 va = ((const float4*)(A + (size_t)(r0 + r) * HD))[c4];
        *((float4*)&As[r * GS + c4 * 4]) = va;
        float4 vb = ((const float4*)(Bt + (size_t)(g0 + r) * HD))[c4];
        *((float4*)&Bs[r * GS + c4 * 4]) = vb;
    }
    __syncthreads();
    int i = tid >> 4;    // 0..15 -> rows i + 16*mi
    int j = tid & 15;    // 0..15 -> cols j + 16*ni
    float acc[4][4];
    #pragma unroll
    for (int a = 0; a < 4; ++a)
        #pragma unroll
        for (int b = 0; b < 4; ++b) acc[a][b] = 0.f;
    #pragma unroll 8
    for (int k4 = 0; k4 < 32; ++k4) {
        float4 av[4], bv[4];
        #pragma unroll
        for (int mi = 0; mi < 4; ++mi)
            av[mi] = *((const float4*)&As[(i + 16 * mi) * GS + k4 * 4]);
        #pragma unroll
        for (int ni = 0; ni < 4; ++ni)
            bv[ni] = *((const float4*)&Bs[(j + 16 * ni) * GS + k4 * 4]);
        #pragma unroll
        for (int mi = 0; mi < 4; ++mi)
            #pragma unroll
            for (int ni = 0; ni < 4; ++ni)
                acc[mi][ni] += (av[mi].x * bv[ni].x + av[mi].y * bv[ni].y) +
                               (av[mi].z * bv[ni].z + av[mi].w * bv[ni].w);
    }
    #pragma unroll
    for (int mi = 0; mi < 4; ++mi)
        #pragma unroll
        for (int ni = 0; ni < 4; ++ni) {
            int g = g0 + j + 16 * ni;
            float bias = (b1 ? b1[g] : 0.f) + (b2 ? b2[g] : 0.f);
            C[(size_t)(r0 + i + 16 * mi) * G + g] = acc[mi][ni] + bias;
        }
}

// ------------------------------------------------------------ GCN aggregation
__global__ __launch_bounds__(128) void k_agg(const int* __restrict__ offs,
                                             const int* __restrict__ csrc,
                                             const float* __restrict__ ca,
                                             const float* __restrict__ xw,
                                             const float* __restrict__ dinv,
                                             const float* __restrict__ bg,
                                             float* __restrict__ hg) {
    int d = blockIdx.x;
    int t = threadIdx.x;
    int beg = offs[d], end = offs[d + 1];
    float acc = 0.f;
    int e = beg;
    for (; e + 3 < end; e += 4) {
        int s0 = csrc[e], s1 = csrc[e + 1], s2 = csrc[e + 2], s3 = csrc[e + 3];
        float a0 = ca[e], a1 = ca[e + 1], a2 = ca[e + 2], a3 = ca[e + 3];
        acc += a0 * xw[(size_t)s0 * HD + t];
        acc += a1 * xw[(size_t)s1 * HD + t];
        acc += a2 * xw[(size_t)s2 * HD + t];
        acc += a3 * xw[(size_t)s3 * HD + t];
    }
    for (; e < end; ++e) acc += ca[e] * xw[(size_t)csrc[e] * HD + t];
    float di = dinv[d];
    hg[(size_t)d * HD + t] = di * acc + di * di * xw[(size_t)d * HD + t] + bg[t];
}

// ----------------------------------------------------------------- LSTM scan
__device__ __forceinline__ float sigm(float x) { return 1.f / (1.f + __expf(-x)); }
__device__ __forceinline__ float tanh_s(float x) {
    float e = __expf(-2.f * fabsf(x));
    float t = (1.f - e) / (1.f + e);
    return copysignf(t, x);
}

// component select that folds to a direct member access under full unroll
#define COMP(v, j) ((j) == 0 ? (v).x : ((j) == 1 ? (v).y : ((j) == 2 ? (v).z : (v).w)))

// 512 threads; thread t owns gate row t (128 weights = 128 VGPRs, pinned).
// h is lane-distributed (hv0/hv1); broadcast via v_readlane (VALU pipe) so the
// LDS return bus (the round-1 bottleneck: 256 KB/step) is bypassed entirely.
__global__ __launch_bounds__(512, 2) void k_lstm(const float* __restrict__ P,
                                                 const float* __restrict__ whh,
                                                 float* __restrict__ Hout,
                                                 float* __restrict__ lastOut) {
    __shared__ float h_sh[HD];
    __shared__ float g_sh[NG];
    int b = blockIdx.x, t = threadIdx.x;
    int lane = t & 63;

    float4 w[32];
    const float4* row = (const float4*)(whh + (size_t)t * HD);
    #pragma unroll
    for (int k = 0; k < 32; ++k) w[k] = row[k];
    // pin 128 weight floats in VGPRs (~170 total demand < 256 cap @ 2 waves/SIMD)
    #pragma unroll
    for (int k = 0; k < 32; ++k)
        asm volatile("" : "+v"(w[k].x), "+v"(w[k].y), "+v"(w[k].z), "+v"(w[k].w));

    float c = 0.f;
    if (t < HD) h_sh[t] = 0.f;
    __syncthreads();

    const float* Pb = P + (size_t)b * SEQ * NG;
    float p = Pb[t];
    bool isG = (t >= 256 && t < 384);

    for (int s = 0; s < SEQ; ++s) {
        const float* Pn = Pb + (size_t)((s + 1 < SEQ) ? (s + 1) : s) * NG;
        float q = Pn[t];                       // prefetch next step's P

        // lane-distributed copy of h: 2 conflict-free b32 reads per thread
        float hv0 = h_sh[lane];
        float hv1 = h_sh[64 + lane];

        float acc[4] = {0.f, 0.f, 0.f, 0.f};
        #pragma unroll
        for (int k = 0; k < 64; ++k) {
            float h = __int_as_float(__builtin_amdgcn_readlane(__float_as_int(hv0), k));
            acc[k & 3] = fmaf(COMP(w[k >> 2], k & 3), h, acc[k & 3]);
        }
        #pragma unroll
        for (int k = 0; k < 64; ++k) {
            float h = __int_as_float(__builtin_amdgcn_readlane(__float_as_int(hv1), k));
            acc[k & 3] = fmaf(COMP(w[16 + (k >> 2)], k & 3), h, acc[k & 3]);
        }
        float raw = ((acc[0] + acc[1]) + (acc[2] + acc[3])) + p;
        float g = isG ? tanh_s(raw) : sigm(raw);
        g_sh[t] = g;
        __syncthreads();

        if (t < HD) {
            float i_ = g_sh[t], f_ = g_sh[128 + t], gg = g_sh[256 + t], o_ = g_sh[384 + t];
            c = fmaf(f_, c, i_ * gg);
            float h = o_ * tanh_s(c);
            h_sh[t] = h;
            if (Hout) Hout[((size_t)b * SEQ + s) * HD + t] = h;
            if (lastOut && s == SEQ - 1) lastOut[b * HD + t] = h;
        }
        __syncthreads();
        p = q;
    }
}

// ----------------------------------------------------------------------- FC
__global__ __launch_bounds__(256) void k_fc(const float* __restrict__ last,
                                            const float* __restrict__ fcw,
                                            const float* __restrict__ fcb,
                                            float* __restrict__ out) {
    __shared__ __align__(16) float l_sh[NB * HD];
    int tid = threadIdx.x;
    #pragma unroll
    for (int it = 0; it < 32; ++it) l_sh[tid + 256 * it] = last[tid + 256 * it];
    __syncthreads();
    int i = blockIdx.x * 256 + tid;
    const float4* wrow = (const float4*)(fcw + (size_t)i * HD);
    float acc[NB];
    #pragma unroll
    for (int b = 0; b < NB; ++b) acc[b] = 0.f;
    for (int k4 = 0; k4 < 32; ++k4) {
        float4 w4 = wrow[k4];
        #pragma unroll
        for (int b = 0; b < NB; ++b) {
            float4 l4 = ((const float4*)(l_sh + b * HD))[k4];
            acc[b] += (w4.x * l4.x + w4.y * l4.y) + (w4.z * l4.z + w4.w * l4.w);
        }
    }
    float bias = fcb[i];
    #pragma unroll
    for (int b = 0; b < NB; ++b) out[(size_t)b * FCN + i] = acc[b] + bias;
}

// -------------------------------------------------------------------- launch
extern "C" void kernel_launch(void* const* d_in, const int* in_sizes, int n_in,
                              void* d_out, int out_size, void* d_ws, size_t ws_size,
                              hipStream_t stream) {
    const float* x   = (const float*)d_in[0];
    const int*   ei  = (const int*)d_in[1];
    const float* ew  = (const float*)d_in[2];
    const float* Wg  = (const float*)d_in[4];
    const float* bg  = (const float*)d_in[5];
    const float* wih = (const float*)d_in[6];   // [2,512,128]
    const float* whh = (const float*)d_in[7];   // [2,512,128]
    const float* bih = (const float*)d_in[8];   // [2,512]
    const float* bhh = (const float*)d_in[9];
    const float* fcw = (const float*)d_in[10];  // [262144,128]
    const float* fcb = (const float*)d_in[11];
    float* out = (float*)d_out;

    float* ws = (float*)d_ws;
    float* deg    = ws;                         // 32768 (-> dinv in place)
    int*   cnt    = (int*)(ws + 32768);         // 32768
    int*   cursor = (int*)(ws + 65536);         // 32768
    int*   offs   = (int*)(ws + 98304);         // 32769
    int*   csrc   = (int*)(ws + 131136);        // 1048576
    float* ca     = ws + 1179712;               // 1048576
    float* Wt     = ws + 2228288;               // 16384
    float* xw     = ws + 2244672;               // 4194304
    float* hg     = ws + 6438976;               // 4194304
    float* H0     = ws + 10633280;              // 4194304
    float* lastb  = ws + 14827584;              // 8192
    float* P      = ws + 14835776;              // 16777216

    // zero deg, cnt, cursor in one shot
    hipMemsetAsync(d_ws, 0, 3 * 32768 * sizeof(float), stream);

    k_deg<<<NEDGE / 256, 256, 0, stream>>>(ei, ew, deg, cnt);
    k_dinv<<<TNODES / 256, 256, 0, stream>>>(deg);
    k_scan<<<1, 1024, 0, stream>>>(cnt, offs);
    k_fill<<<NEDGE / 256, 256, 0, stream>>>(ei, ew, deg, offs, cursor, csrc, ca);
    k_transpose<<<64, 256, 0, stream>>>(Wg, Wt);
    k_gemm_bt<<<dim3(TNODES / 64, HD / 64), 256, 0, stream>>>(x, Wt, nullptr, nullptr, xw, HD);
    k_agg<<<TNODES, 128, 0, stream>>>(offs, csrc, ca, xw, deg, bg, hg);

    // layer 0
    k_gemm_bt<<<dim3(TNODES / 64, NG / 64), 256, 0, stream>>>(hg, wih, bih, bhh, P, NG);
    k_lstm<<<NB, 512, 0, stream>>>(P, whh, H0, nullptr);
    // layer 1
    k_gemm_bt<<<dim3(TNODES / 64, NG / 64), 256, 0, stream>>>(H0, wih + 65536, bih + 512, bhh + 512, P, NG);
    k_lstm<<<NB, 512, 0, stream>>>(P, whh + 65536, nullptr, lastb);

    k_fc<<<FCN / 256, 256, 0, stream>>>(lastb, fcw, fcb, out);
}

// Round 4
// 1674.586 us; speedup vs baseline: 1.3729x; 1.2817x over previous
//
#include <hip/hip_runtime.h>

#define TNODES 32768
#define NEDGE  1048576
#define HD     128
#define NG     512     // 4*H gates
#define NB     64
#define SEQ    512
#define FCN    262144  // N_NODES^2

// ---------------------------------------------------------------- GCN: degree
__global__ __launch_bounds__(256) void k_deg(const int* __restrict__ ei,
                                             const float* __restrict__ ew,
                                             float* __restrict__ deg,
                                             int* __restrict__ cnt) {
    int e = blockIdx.x * 256 + threadIdx.x;
    int d = ei[NEDGE + e];          // dst row
    atomicAdd(&deg[d], ew[e]);
    atomicAdd(&cnt[d], 1);
}

__global__ __launch_bounds__(256) void k_dinv(float* __restrict__ deg) {
    int n = blockIdx.x * 256 + threadIdx.x;
    deg[n] = rsqrtf(deg[n] + 1.0f);   // self-loop w=1; deg>=1 always
}

// exclusive prefix scan of cnt[32768] -> offs[32769], single block
__global__ __launch_bounds__(1024) void k_scan(const int* __restrict__ cnt,
                                               int* __restrict__ offs) {
    __shared__ int sums[1024];
    int t = threadIdx.x;
    int base = t * 32;
    int local[32];
    int s = 0;
    #pragma unroll
    for (int j = 0; j < 32; ++j) { local[j] = s; s += cnt[base + j]; }
    sums[t] = s;
    __syncthreads();
    for (int off = 1; off < 1024; off <<= 1) {
        int v = sums[t];
        int u = (t >= off) ? sums[t - off] : 0;
        __syncthreads();
        sums[t] = v + u;
        __syncthreads();
    }
    int baseSum = (t == 0) ? 0 : sums[t - 1];
    #pragma unroll
    for (int j = 0; j < 32; ++j) offs[base + j] = baseSum + local[j];
    if (t == 1023) offs[TNODES] = sums[1023];
}

__global__ __launch_bounds__(256) void k_fill(const int* __restrict__ ei,
                                              const float* __restrict__ ew,
                                              const float* __restrict__ dinv,
                                              const int* __restrict__ offs,
                                              int* __restrict__ cursor,
                                              int* __restrict__ csrc,
                                              float* __restrict__ ca) {
    int e = blockIdx.x * 256 + threadIdx.x;
    int s = ei[e];
    int d = ei[NEDGE + e];
    int p = offs[d] + atomicAdd(&cursor[d], 1);
    csrc[p] = s;
    ca[p] = ew[e] * dinv[s];
}

// ------------------------------------------------- tiny transpose W_gcn -> Wt
__global__ __launch_bounds__(256) void k_transpose(const float* __restrict__ W,
                                                   float* __restrict__ Wt) {
    int t = blockIdx.x * 256 + threadIdx.x;   // 16384
    int c = t >> 7, k = t & 127;
    Wt[t] = W[k * HD + c];
}

// -------------------------------------------- generic C[R,G] = A[R,128]@Bt^T
// Bt is [G,128]; bias = bias1[g]+bias2[g] (either may be null). 64x64 tiles.
#define GS 140
__global__ __launch_bounds__(256) void k_gemm_bt(const float* __restrict__ A,
                                                 const float* __restrict__ Bt,
                                                 const float* __restrict__ b1,
                                                 const float* __restrict__ b2,
                                                 float* __restrict__ C, int G) {
    __shared__ __align__(16) float As[64 * GS];
    __shared__ __align__(16) float Bs[64 * GS];
    int r0 = blockIdx.x * 64;
    int g0 = blockIdx.y * 64;
    int tid = threadIdx.x;
    #pragma unroll
    for (int it = 0; it < 8; ++it) {
        int idx = tid + 256 * it;        // 0..2047
        int r = idx >> 5, c4 = idx & 31;
        float4 va = ((const float4*)(A + (size_t)(r0 + r) * HD))[c4];
        *((float4*)&As[r * GS + c4 * 4]) = va;
        float4 vb = ((const float4*)(Bt + (size_t)(g0 + r) * HD))[c4];
        *((float4*)&Bs[r * GS + c4 * 4]) = vb;
    }
    __syncthreads();
    int i = tid >> 4;    // 0..15 -> rows i + 16*mi
    int j = tid & 15;    // 0..15 -> cols j + 16*ni
    float acc[4][4];
    #pragma unroll
    for (int a = 0; a < 4; ++a)
        #pragma unroll
        for (int b = 0; b < 4; ++b) acc[a][b] = 0.f;
    #pragma unroll 8
    for (int k4 = 0; k4 < 32; ++k4) {
        float4 av[4], bv[4];
        #pragma unroll
        for (int mi = 0; mi < 4; ++mi)
            av[mi] = *((const float4*)&As[(i + 16 * mi) * GS + k4 * 4]);
        #pragma unroll
        for (int ni = 0; ni < 4; ++ni)
            bv[ni] = *((const float4*)&Bs[(j + 16 * ni) * GS + k4 * 4]);
        #pragma unroll
        for (int mi = 0; mi < 4; ++mi)
            #pragma unroll
            for (int ni = 0; ni < 4; ++ni)
                acc[mi][ni] += (av[mi].x * bv[ni].x + av[mi].y * bv[ni].y) +
                               (av[mi].z * bv[ni].z + av[mi].w * bv[ni].w);
    }
    #pragma unroll
    for (int mi = 0; mi < 4; ++mi)
        #pragma unroll
        for (int ni = 0; ni < 4; ++ni) {
            int g = g0 + j + 16 * ni;
            float bias = (b1 ? b1[g] : 0.f) + (b2 ? b2[g] : 0.f);
            C[(size_t)(r0 + i + 16 * mi) * G + g] = acc[mi][ni] + bias;
        }
}

// ------------------------------------------------------------ GCN aggregation
__global__ __launch_bounds__(128) void k_agg(const int* __restrict__ offs,
                                             const int* __restrict__ csrc,
                                             const float* __restrict__ ca,
                                             const float* __restrict__ xw,
                                             const float* __restrict__ dinv,
                                             const float* __restrict__ bg,
                                             float* __restrict__ hg) {
    int d = blockIdx.x;
    int t = threadIdx.x;
    int beg = offs[d], end = offs[d + 1];
    float acc = 0.f;
    int e = beg;
    for (; e + 3 < end; e += 4) {
        int s0 = csrc[e], s1 = csrc[e + 1], s2 = csrc[e + 2], s3 = csrc[e + 3];
        float a0 = ca[e], a1 = ca[e + 1], a2 = ca[e + 2], a3 = ca[e + 3];
        acc += a0 * xw[(size_t)s0 * HD + t];
        acc += a1 * xw[(size_t)s1 * HD + t];
        acc += a2 * xw[(size_t)s2 * HD + t];
        acc += a3 * xw[(size_t)s3 * HD + t];
    }
    for (; e < end; ++e) acc += ca[e] * xw[(size_t)csrc[e] * HD + t];
    float di = dinv[d];
    hg[(size_t)d * HD + t] = di * acc + di * di * xw[(size_t)d * HD + t] + bg[t];
}

// ----------------------------------------------------------------- LSTM scan
__device__ __forceinline__ float sigm(float x) { return 1.f / (1.f + __expf(-x)); }
__device__ __forceinline__ float tanh_s(float x) {
    float e = __expf(-2.f * fabsf(x));
    float t = (1.f - e) / (1.f + e);
    return copysignf(t, x);
}

// component select that folds to a direct member access under full unroll
#define COMP(v, j) ((j) == 0 ? (v).x : ((j) == 1 ? (v).y : ((j) == 2 ? (v).z : (v).w)))

// 512 threads. Thread (c = t>>7, i = t&127) holds gate rows {i,i+128,i+256,i+384}
// (= gates i,f,g,o of hidden unit i) restricted to k in [32c, 32c+32):
// 128 weight floats in VGPRs. Weights are staged through an LDS buffer that is
// later clobbered (reused as the partial buffer) so the compiler CANNOT remat
// the loads inside the loop; no asm pins (round-3 scratch pathology).
// h broadcast: 32 readlanes amortized over 128 FMAs. 2 barriers/step.
__global__ __launch_bounds__(512, 2) void k_lstm(const float* __restrict__ P,
                                                 const float* __restrict__ whh,
                                                 float* __restrict__ Hout,
                                                 float* __restrict__ lastOut) {
    __shared__ __align__(16) float lds[18560];   // staging [0,18432) aliased by
                                                 // partials [0,2048); h at 18432
    float* h_sh = lds + 18432;                   // [128]
    int b = blockIdx.x, t = threadIdx.x;
    int c = t >> 7;        // k-chunk
    int i = t & 127;       // hidden unit (this thread's 4 gate rows)

    // ---- stage whh through LDS in 4 k-chunks; pull fragments into registers
    float4 w[4][8];        // [gate][q]: k = 32c + 4q .. +3
    for (int cc = 0; cc < 4; ++cc) {
        const float4* src = (const float4*)(whh + (size_t)t * HD + 32 * cc);
        float4 tmp[8];
        #pragma unroll
        for (int q = 0; q < 8; ++q) tmp[q] = src[q];
        __syncthreads();
        #pragma unroll
        for (int q = 0; q < 8; ++q)
            *((float4*)(lds + t * 36 + 4 * q)) = tmp[q];   // row stride 36 (pad)
        __syncthreads();
        if (cc == c) {
            #pragma unroll
            for (int g = 0; g < 4; ++g)
                #pragma unroll
                for (int q = 0; q < 8; ++q)
                    w[g][q] = *((const float4*)(lds + (i + 128 * g) * 36 + 4 * q));
        }
    }
    __syncthreads();

    if (t < HD) h_sh[t] = 0.f;
    float cst = 0.f;
    const float* Pb = P + (size_t)b * SEQ * NG;
    float pi = 0.f, pf = 0.f, pg = 0.f, po = 0.f;
    if (t < HD) { pi = Pb[t]; pf = Pb[128 + t]; pg = Pb[256 + t]; po = Pb[384 + t]; }
    __syncthreads();

    for (int s = 0; s < SEQ; ++s) {
        // lanes 0..31 of each wave hold h[32c .. 32c+32) (lanes 32..63 dup)
        float hv = h_sh[32 * c + (t & 31)];
        float4 acc = {0.f, 0.f, 0.f, 0.f};
        #pragma unroll
        for (int k = 0; k < 32; ++k) {
            float h = __int_as_float(__builtin_amdgcn_readlane(__float_as_int(hv), k));
            acc.x = fmaf(COMP(w[0][k >> 2], k & 3), h, acc.x);
            acc.y = fmaf(COMP(w[1][k >> 2], k & 3), h, acc.y);
            acc.z = fmaf(COMP(w[2][k >> 2], k & 3), h, acc.z);
            acc.w = fmaf(COMP(w[3][k >> 2], k & 3), h, acc.w);
        }
        ((float4*)lds)[c * 128 + i] = acc;     // part[c][i][gate] (clobbers staging)
        __syncthreads();

        if (t < HD) {
            float4 s0 = ((const float4*)lds)[t];
            float4 s1 = ((const float4*)lds)[128 + t];
            float4 s2 = ((const float4*)lds)[256 + t];
            float4 s3 = ((const float4*)lds)[384 + t];
            float gi = (s0.x + s1.x) + (s2.x + s3.x) + pi;
            float gf = (s0.y + s1.y) + (s2.y + s3.y) + pf;
            float gg = (s0.z + s1.z) + (s2.z + s3.z) + pg;
            float go = (s0.w + s1.w) + (s2.w + s3.w) + po;
            float i_ = sigm(gi), f_ = sigm(gf), g_ = tanh_s(gg), o_ = sigm(go);
            cst = fmaf(f_, cst, i_ * g_);
            float h = o_ * tanh_s(cst);
            h_sh[t] = h;
            if (Hout) Hout[((size_t)b * SEQ + s) * HD + t] = h;
            if (lastOut && s == SEQ - 1) lastOut[b * HD + t] = h;
            if (s + 1 < SEQ) {
                const float* Pn = Pb + (size_t)(s + 1) * NG;
                pi = Pn[t]; pf = Pn[128 + t]; pg = Pn[256 + t]; po = Pn[384 + t];
            }
        }
        __syncthreads();
    }
}

// ----------------------------------------------------------------------- FC
__global__ __launch_bounds__(256) void k_fc(const float* __restrict__ last,
                                            const float* __restrict__ fcw,
                                            const float* __restrict__ fcb,
                                            float* __restrict__ out) {
    __shared__ __align__(16) float l_sh[NB * HD];
    int tid = threadIdx.x;
    #pragma unroll
    for (int it = 0; it < 32; ++it) l_sh[tid + 256 * it] = last[tid + 256 * it];
    __syncthreads();
    int i = blockIdx.x * 256 + tid;
    const float4* wrow = (const float4*)(fcw + (size_t)i * HD);
    float acc[NB];
    #pragma unroll
    for (int b = 0; b < NB; ++b) acc[b] = 0.f;
    for (int k4 = 0; k4 < 32; ++k4) {
        float4 w4 = wrow[k4];
        #pragma unroll
        for (int b = 0; b < NB; ++b) {
            float4 l4 = ((const float4*)(l_sh + b * HD))[k4];
            acc[b] += (w4.x * l4.x + w4.y * l4.y) + (w4.z * l4.z + w4.w * l4.w);
        }
    }
    float bias = fcb[i];
    #pragma unroll
    for (int b = 0; b < NB; ++b) out[(size_t)b * FCN + i] = acc[b] + bias;
}

// -------------------------------------------------------------------- launch
extern "C" void kernel_launch(void* const* d_in, const int* in_sizes, int n_in,
                              void* d_out, int out_size, void* d_ws, size_t ws_size,
                              hipStream_t stream) {
    const float* x   = (const float*)d_in[0];
    const int*   ei  = (const int*)d_in[1];
    const float* ew  = (const float*)d_in[2];
    const float* Wg  = (const float*)d_in[4];
    const float* bg  = (const float*)d_in[5];
    const float* wih = (const float*)d_in[6];   // [2,512,128]
    const float* whh = (const float*)d_in[7];   // [2,512,128]
    const float* bih = (const float*)d_in[8];   // [2,512]
    const float* bhh = (const float*)d_in[9];
    const float* fcw = (const float*)d_in[10];  // [262144,128]
    const float* fcb = (const float*)d_in[11];
    float* out = (float*)d_out;

    float* ws = (float*)d_ws;
    float* deg    = ws;                         // 32768 (-> dinv in place)
    int*   cnt    = (int*)(ws + 32768);         // 32768
    int*   cursor = (int*)(ws + 65536);         // 32768
    int*   offs   = (int*)(ws + 98304);         // 32769
    int*   csrc   = (int*)(ws + 131136);        // 1048576
    float* ca     = ws + 1179712;               // 1048576
    float* Wt     = ws + 2228288;               // 16384
    float* xw     = ws + 2244672;               // 4194304
    float* hg     = ws + 6438976;               // 4194304
    float* H0     = ws + 10633280;              // 4194304
    float* lastb  = ws + 14827584;              // 8192
    float* P      = ws + 14835776;              // 16777216

    // zero deg, cnt, cursor in one shot
    hipMemsetAsync(d_ws, 0, 3 * 32768 * sizeof(float), stream);

    k_deg<<<NEDGE / 256, 256, 0, stream>>>(ei, ew, deg, cnt);
    k_dinv<<<TNODES / 256, 256, 0, stream>>>(deg);
    k_scan<<<1, 1024, 0, stream>>>(cnt, offs);
    k_fill<<<NEDGE / 256, 256, 0, stream>>>(ei, ew, deg, offs, cursor, csrc, ca);
    k_transpose<<<64, 256, 0, stream>>>(Wg, Wt);
    k_gemm_bt<<<dim3(TNODES / 64, HD / 64), 256, 0, stream>>>(x, Wt, nullptr, nullptr, xw, HD);
    k_agg<<<TNODES, 128, 0, stream>>>(offs, csrc, ca, xw, deg, bg, hg);

    // layer 0
    k_gemm_bt<<<dim3(TNODES / 64, NG / 64), 256, 0, stream>>>(hg, wih, bih, bhh, P, NG);
    k_lstm<<<NB, 512, 0, stream>>>(P, whh, H0, nullptr);
    // layer 1
    k_gemm_bt<<<dim3(TNODES / 64, NG / 64), 256, 0, stream>>>(H0, wih + 65536, bih + 512, bhh + 512, P, NG);
    k_lstm<<<NB, 512, 0, stream>>>(P, whh + 65536, nullptr, lastb);

    k_fc<<<FCN / 256, 256, 0, stream>>>(lastb, fcw, fcb, out);
}